// Round 1
// baseline (12271.586 us; speedup 1.0000x reference)
//
#include <hip/hip_runtime.h>

#define H 128
#define ED 64

// stats layout: [0:128) colsum, [128:256) colsumsq, [256:384) scale, [384:512) shift
__device__ __align__(16) float g_stats[512];

__global__ void k_zero_stats() {
    if (threadIdx.x < 512) g_stats[threadIdx.x] = 0.f;
}

// -------- Edge kernel: msg = relu(h[src] + ea@W_edge + b_edge); atomic agg[dst] += msg
__global__ __launch_bounds__(256, 4) void k_edge(
    const float* __restrict__ hN, const int* __restrict__ ei,
    const float* __restrict__ ea, const float* __restrict__ We,
    const float* __restrict__ be, float* __restrict__ agg, int E)
{
    __shared__ __align__(16) float sW[ED * H];        // 32 KB
    __shared__ __align__(16) float sEA[4][4][ED];     // 4 KB (wave, edge-slot, k)
    const int tid = threadIdx.x;
    for (int i = tid; i < (ED * H) / 4; i += 256)
        ((float4*)sW)[i] = ((const float4*)We)[i];
    __syncthreads();

    const int w = tid >> 6, lane = tid & 63;
    const int c = lane << 1;                           // columns {c, c+1}
    const float2 bb = *(const float2*)&be[c];
    const int waveId = (blockIdx.x << 2) | w;
    const int nWaves = gridDim.x << 2;
    const int nGroups = (E + 3) >> 2;

    for (int g = waveId; g < nGroups; g += nWaves) {
        const int e0 = g << 2;
        // stage 4 edges' ea rows (per-wave buffer, wave-synchronous)
#pragma unroll
        for (int j = 0; j < 4; ++j) {
            int e = e0 + j;
            if (e < E) sEA[w][j][lane] = ea[(size_t)e * ED + lane];
        }
        __builtin_amdgcn_wave_barrier();

        float ax[4], ay[4];
#pragma unroll
        for (int j = 0; j < 4; ++j) { ax[j] = bb.x; ay[j] = bb.y; }

#pragma unroll
        for (int k0 = 0; k0 < ED; k0 += 4) {
            float av[4][4];
#pragma unroll
            for (int j = 0; j < 4; ++j) {
                float4 t = *(const float4*)&sEA[w][j][k0];
                av[j][0] = t.x; av[j][1] = t.y; av[j][2] = t.z; av[j][3] = t.w;
            }
#pragma unroll
            for (int kk = 0; kk < 4; ++kk) {
                float2 wv = *(const float2*)&sW[(k0 + kk) * H + c];
#pragma unroll
                for (int j = 0; j < 4; ++j) {
                    ax[j] = fmaf(av[j][kk], wv.x, ax[j]);
                    ay[j] = fmaf(av[j][kk], wv.y, ay[j]);
                }
            }
        }

#pragma unroll
        for (int j = 0; j < 4; ++j) {
            int e = e0 + j;
            if (e < E) {
                int s = ei[e];
                int d = ei[E + e];
                float2 hv = *(const float2*)&hN[(size_t)s * H + c];
                float v0 = fmaxf(ax[j] + hv.x, 0.f);
                float v1 = fmaxf(ay[j] + hv.y, 0.f);
                atomicAdd(&agg[(size_t)d * H + c],     v0);
                atomicAdd(&agg[(size_t)d * H + c + 1], v1);
            }
        }
        __builtin_amdgcn_wave_barrier();
    }
}

// -------- Node MLP kernel: z2 = relu(relu(((1+eps)h + agg)@W1 + b1)@W2 + b2)
// reads agg from zb (=d_out), writes z2 back in place; accumulates BN col sums.
__global__ __launch_bounds__(512, 2) void k_mlp(
    const float* __restrict__ hN, float* __restrict__ zb,
    const float* __restrict__ W1, const float* __restrict__ b1,
    const float* __restrict__ W2, const float* __restrict__ b2,
    const float* __restrict__ epsp, int N)
{
    __shared__ __align__(16) float sW1[H * H];        // 64 KB
    __shared__ __align__(16) float sW2[H * H];        // 64 KB
    __shared__ __align__(16) float sB[8][4][H];       // 16 KB (wave, node-slot, k)
    __shared__ float sRed[2 * H];                     // 1 KB
    const int tid = threadIdx.x;
    for (int i = tid; i < (H * H) / 4; i += 512) {
        ((float4*)sW1)[i] = ((const float4*)W1)[i];
        ((float4*)sW2)[i] = ((const float4*)W2)[i];
    }
    if (tid < 2 * H) sRed[tid] = 0.f;
    __syncthreads();

    const int w = tid >> 6, lane = tid & 63;
    const int c = lane << 1;
    const float e1 = 1.f + epsp[0];
    const float2 bb1 = *(const float2*)&b1[c];
    const float2 bb2 = *(const float2*)&b2[c];
    float s0 = 0.f, s1 = 0.f, q0 = 0.f, q1 = 0.f;

    const int waveId = (blockIdx.x << 3) | w;
    const int nWaves = gridDim.x << 3;
    const int nGroups = (N + 3) >> 2;

    for (int g = waveId; g < nGroups; g += nWaves) {
        const int n0 = g << 2;
        // stage z = (1+eps)*h + agg for 4 nodes
#pragma unroll
        for (int j = 0; j < 4; ++j) {
            int n = n0 + j;
            if (n < N) {
                size_t off = (size_t)n * H + c;
                float2 hv = *(const float2*)&hN[off];
                float2 av = *(const float2*)&zb[off];
                float2 zv;
                zv.x = fmaf(e1, hv.x, av.x);
                zv.y = fmaf(e1, hv.y, av.y);
                *(float2*)&sB[w][j][c] = zv;
            }
        }
        __builtin_amdgcn_wave_barrier();

        // layer 1
        float ax[4], ay[4];
#pragma unroll
        for (int j = 0; j < 4; ++j) { ax[j] = bb1.x; ay[j] = bb1.y; }
#pragma unroll 4
        for (int k0 = 0; k0 < H; k0 += 4) {
            float zv[4][4];
#pragma unroll
            for (int j = 0; j < 4; ++j) {
                float4 t = *(const float4*)&sB[w][j][k0];
                zv[j][0] = t.x; zv[j][1] = t.y; zv[j][2] = t.z; zv[j][3] = t.w;
            }
#pragma unroll
            for (int kk = 0; kk < 4; ++kk) {
                float2 wv = *(const float2*)&sW1[(k0 + kk) * H + c];
#pragma unroll
                for (int j = 0; j < 4; ++j) {
                    ax[j] = fmaf(zv[j][kk], wv.x, ax[j]);
                    ay[j] = fmaf(zv[j][kk], wv.y, ay[j]);
                }
            }
        }
        // relu + restage y1 (reuse sB; all reads completed in program order)
#pragma unroll
        for (int j = 0; j < 4; ++j) {
            float2 yv;
            yv.x = fmaxf(ax[j], 0.f);
            yv.y = fmaxf(ay[j], 0.f);
            *(float2*)&sB[w][j][c] = yv;
        }
        __builtin_amdgcn_wave_barrier();

        // layer 2
        float cx[4], cy[4];
#pragma unroll
        for (int j = 0; j < 4; ++j) { cx[j] = bb2.x; cy[j] = bb2.y; }
#pragma unroll 4
        for (int k0 = 0; k0 < H; k0 += 4) {
            float yv[4][4];
#pragma unroll
            for (int j = 0; j < 4; ++j) {
                float4 t = *(const float4*)&sB[w][j][k0];
                yv[j][0] = t.x; yv[j][1] = t.y; yv[j][2] = t.z; yv[j][3] = t.w;
            }
#pragma unroll
            for (int kk = 0; kk < 4; ++kk) {
                float2 wv = *(const float2*)&sW2[(k0 + kk) * H + c];
#pragma unroll
                for (int j = 0; j < 4; ++j) {
                    cx[j] = fmaf(yv[j][kk], wv.x, cx[j]);
                    cy[j] = fmaf(yv[j][kk], wv.y, cy[j]);
                }
            }
        }
        __builtin_amdgcn_wave_barrier();

        // epilogue: z2 = relu(y2); store; BN partial sums
#pragma unroll
        for (int j = 0; j < 4; ++j) {
            int n = n0 + j;
            if (n < N) {
                float z2x = fmaxf(cx[j], 0.f);
                float z2y = fmaxf(cy[j], 0.f);
                size_t off = (size_t)n * H + c;
                float2 o; o.x = z2x; o.y = z2y;
                *(float2*)&zb[off] = o;
                s0 += z2x; s1 += z2y;
                q0 += z2x * z2x; q1 += z2y * z2y;
            }
        }
    }

    // block-level BN reduction, then one global atomic per column
    __syncthreads();
    atomicAdd(&sRed[c],     s0);
    atomicAdd(&sRed[c + 1], s1);
    atomicAdd(&sRed[H + c],     q0);
    atomicAdd(&sRed[H + c + 1], q1);
    __syncthreads();
    if (tid < H) {
        atomicAdd(&g_stats[tid],     sRed[tid]);
        atomicAdd(&g_stats[H + tid], sRed[H + tid]);
    }
}

// -------- BN finalize: scale/shift per column
__global__ void k_bnfin(const float* __restrict__ gamma, const float* __restrict__ beta,
                        float invN)
{
    int t = threadIdx.x; // 128 threads
    float mean = g_stats[t] * invN;
    float var  = g_stats[H + t] * invN - mean * mean;
    float sc = gamma[t] * rsqrtf(var + 1e-5f);
    g_stats[256 + t] = sc;
    g_stats[384 + t] = beta[t] - mean * sc;
}

// -------- Final: out = (h + z2*scale + shift) * valid_f   (in place on d_out)
__global__ void k_final(const float* __restrict__ hN, const float* __restrict__ valid,
                        float* __restrict__ out, int N)
{
    const int total = N * (H / 4);
    for (int i = blockIdx.x * blockDim.x + threadIdx.x; i < total;
         i += gridDim.x * blockDim.x) {
        int col4 = i & 31;          // H/4 = 32 float4 per row
        int n = i >> 5;
        float4 z = ((float4*)out)[i];
        float4 hv = ((const float4*)hN)[i];
        float4 sc = *(const float4*)&g_stats[256 + col4 * 4];
        float4 sh = *(const float4*)&g_stats[384 + col4 * 4];
        float vf = valid[n];
        float4 r;
        r.x = (hv.x + fmaf(z.x, sc.x, sh.x)) * vf;
        r.y = (hv.y + fmaf(z.y, sc.y, sh.y)) * vf;
        r.z = (hv.z + fmaf(z.z, sc.z, sh.z)) * vf;
        r.w = (hv.w + fmaf(z.w, sc.w, sh.w)) * vf;
        ((float4*)out)[i] = r;
    }
}

extern "C" void kernel_launch(void* const* d_in, const int* in_sizes, int n_in,
                              void* d_out, int out_size, void* d_ws, size_t ws_size,
                              hipStream_t stream) {
    const float* hN    = (const float*)d_in[0];
    const int*   ei    = (const int*)d_in[1];
    const float* ea    = (const float*)d_in[2];
    const float* valid = (const float*)d_in[3];
    const float* We    = (const float*)d_in[4];
    const float* be    = (const float*)d_in[5];
    const float* W1    = (const float*)d_in[6];
    const float* b1    = (const float*)d_in[7];
    const float* W2    = (const float*)d_in[8];
    const float* b2    = (const float*)d_in[9];
    const float* epsg  = (const float*)d_in[10];
    const float* gamma = (const float*)d_in[11];
    const float* beta  = (const float*)d_in[12];
    float* out = (float*)d_out;

    const int N = in_sizes[0] / H;
    const int E = in_sizes[1] / 2;

    // agg accumulates into d_out; zero it each call (harness does not re-poison)
    hipMemsetAsync(d_out, 0, (size_t)out_size * sizeof(float), stream);
    k_zero_stats<<<1, 512, 0, stream>>>();
    k_edge<<<2048, 256, 0, stream>>>(hN, ei, ea, We, be, out, E);
    k_mlp<<<512, 512, 0, stream>>>(hN, out, W1, b1, W2, b2, epsg, N);
    k_bnfin<<<1, 128, 0, stream>>>(gamma, beta, 1.0f / (float)N);
    k_final<<<2048, 256, 0, stream>>>(hN, valid, out, N);
}